// Round 6
// baseline (1647.080 us; speedup 1.0000x reference)
//
#include <hip/hip_runtime.h>

#define N_NODES 100000
#define N_EDGES 3200000
#define NF 256
#define HID 64
#define BSHIFT 7
#define NBUCK 782                       // ceil(100000 / 128)
#define NP1 512                         // phase-1 partition blocks
#define CHUNKE (N_EDGES / NP1)          // 6250 exactly
#define TB 16                           // buckets per bktAC block
#define ASTR 65                         // acc row stride (floats) — bank spread

typedef short short8 __attribute__((ext_vector_type(8)));
typedef float f32x4 __attribute__((ext_vector_type(4)));

__device__ __forceinline__ unsigned short f2bf(float v) {
    unsigned int u = __float_as_uint(v);
    u += 0x7FFFu + ((u >> 16) & 1u);
    return (unsigned short)(u >> 16);
}
__device__ __forceinline__ float bfl(unsigned int p) { return __uint_as_float((p & 0xFFFFu) << 16); }
__device__ __forceinline__ float bfh(unsigned int p) { return __uint_as_float(p & 0xFFFF0000u); }

// ---------- 1a: per-block LDS histogram -> blkhist[block][bucket] (coalesced row) ----------
__launch_bounds__(256)
__global__ void p1count(const int* __restrict__ ei, unsigned int* __restrict__ blkhist) {
    __shared__ unsigned int hist[NBUCK];
    for (int i = threadIdx.x; i < NBUCK; i += 256) hist[i] = 0;
    __syncthreads();
    int lo = blockIdx.x * CHUNKE;
    int hi = lo + CHUNKE;
    for (int e = lo + threadIdx.x; e < hi; e += 256)
        atomicAdd(&hist[((unsigned)ei[N_EDGES + e]) >> BSHIFT], 1u);
    __syncthreads();
    unsigned int* row = blkhist + (size_t)blockIdx.x * NBUCK;
    for (int i = threadIdx.x; i < NBUCK; i += 256) row[i] = hist[i];
}

// ---------- 1bd merged: coalesced tiled transpose-scan ----------
__launch_bounds__(256)
__global__ void bktAC(const unsigned int* __restrict__ blkhist,
                      unsigned int* __restrict__ total, unsigned int* __restrict__ blkbase) {
    __shared__ unsigned int tile[NP1][TB + 1];   // 512*17*4 = 34816 B
    __shared__ unsigned int part[16][TB + 1];
    int t = threadIdx.x;
    int i0 = blockIdx.x * TB;
    int q = t & 15;           // bucket within tile
    int r = t >> 4;           // 0..15

    for (int b = r; b < NP1; b += 16) {
        int ib = i0 + q;
        tile[b][q] = (ib < NBUCK) ? blkhist[(size_t)b * NBUCK + ib] : 0u;
    }
    __syncthreads();

    unsigned s = 0;
    int b0 = r * 32;
    for (int b = b0; b < b0 + 32; ++b) s += tile[b][q];
    part[r][q] = s;
    __syncthreads();
    for (int off = 1; off < 16; off <<= 1) {
        unsigned a = (r >= off) ? part[r - off][q] : 0u;
        __syncthreads();
        part[r][q] += a;
        __syncthreads();
    }
    unsigned run = part[r][q] - s;
    if (r == 15 && i0 + q < NBUCK) total[i0 + q] = part[15][q];
    for (int b = b0; b < b0 + 32; ++b) {
        unsigned v = tile[b][q];
        tile[b][q] = run;
        run += v;
    }
    __syncthreads();

    for (int qq = 0; qq < TB; ++qq) {
        int ib = i0 + qq;
        if (ib < NBUCK) {
            for (int b = t; b < NP1; b += 256)
                blkbase[(size_t)ib * NP1 + b] = tile[b][qq];
        }
    }
}

// ---------- 1c: exclusive scan of bucket totals -> bucket_base ----------
__launch_bounds__(1024)
__global__ void bktB(const unsigned int* __restrict__ total, unsigned int* __restrict__ base) {
    __shared__ unsigned int sh[1024];
    int t = threadIdx.x;
    unsigned v = (t < NBUCK) ? total[t] : 0;
    sh[t] = v;
    __syncthreads();
    for (int off = 1; off < 1024; off <<= 1) {
        unsigned a = (t >= off) ? sh[t - off] : 0;
        __syncthreads();
        sh[t] += a;
        __syncthreads();
    }
    if (t < NBUCK) base[t] = sh[t] - v;
    if (t == 0) base[NBUCK] = N_EDGES;
}

// ---------- 1e: staged scatter — LDS counting sort, then coalesced run write-out ----------
// pbuf entry: x = src | (dst_low7 << 17), y = ew bits
__launch_bounds__(256)
__global__ void p1scatter(const int* __restrict__ ei, const float* __restrict__ ew,
                          const unsigned int* __restrict__ blkhist,
                          const unsigned int* __restrict__ base,
                          const unsigned int* __restrict__ blkbase, int2* __restrict__ pbuf) {
    __shared__ int2 sorted[CHUNKE];           // 50000 B
    __shared__ unsigned int loff[NBUCK + 2];
    __shared__ unsigned int cur[NBUCK];
    __shared__ unsigned int gbase[NBUCK];
    __shared__ unsigned int sh[256];

    int t = threadIdx.x;
    int b = blockIdx.x;

    for (int i = t; i < NBUCK; i += 256) gbase[i] = base[i];

    unsigned u[4];
    unsigned s = 0;
#pragma unroll
    for (int j = 0; j < 4; ++j) {
        int idx = 4 * t + j;
        u[j] = (idx < NBUCK) ? blkhist[(size_t)b * NBUCK + idx] : 0u;
        s += u[j];
    }
    sh[t] = s;
    __syncthreads();
    for (int off = 1; off < 256; off <<= 1) {
        unsigned a = (t >= off) ? sh[t - off] : 0;
        __syncthreads();
        sh[t] += a;
        __syncthreads();
    }
    unsigned run = sh[t] - s;
#pragma unroll
    for (int j = 0; j < 4; ++j) {
        int idx = 4 * t + j;
        if (idx <= NBUCK) loff[idx] = run;
        run += u[j];
        if (idx < NBUCK) cur[idx] = 0;
    }
    __syncthreads();

    int lo = b * CHUNKE;
    int hi = lo + CHUNKE;
    for (int e = lo + t; e < hi; e += 256) {
        int src = ei[e];
        unsigned d = (unsigned)ei[N_EDGES + e];
        unsigned k = d >> BSHIFT;
        unsigned r = atomicAdd(&cur[k], 1u);
        sorted[loff[k] + r] = make_int2(src | (int)((d & 127u) << 17), __float_as_int(ew[e]));
    }
    __syncthreads();

    int lane = t & 63;
    int wave = t >> 6;
    int q = lane >> 3;
    int r8 = lane & 7;
    for (int k0 = wave * 8; k0 < NBUCK; k0 += 32) {
        int k = k0 + q;
        if (k < NBUCK) {
            unsigned off = loff[k];
            int n = (int)(loff[k + 1] - off);
            unsigned gb = gbase[k] + blkbase[(size_t)k * NP1 + b];
            for (int i = r8; i < n; i += 8)
                pbuf[gb + i] = sorted[off + i];
        }
    }
}

// ---------- phase 2: weighted degree + dinv only (no sort, no ebuf, no CSR) ----------
__launch_bounds__(256)
__global__ void p2deg(const int2* __restrict__ pbuf, const unsigned int* __restrict__ base,
                      float* __restrict__ dinv) {
    __shared__ float ldeg[128];
    int t = threadIdx.x;
    int bkt = blockIdx.x;
    if (t < 128) ldeg[t] = 0.f;
    __syncthreads();
    unsigned lo = base[bkt], hi = base[bkt + 1];
    for (unsigned i = lo + t; i < hi; i += 256) {
        int2 e = pbuf[i];
        atomicAdd(&ldeg[(e.x >> 17) & 127], __int_as_float(e.y));
    }
    __syncthreads();
    int d0 = bkt << BSHIFT;
    if (t < 128 && d0 + t < N_NODES) dinv[d0 + t] = rsqrtf(ldeg[t] + 1.0f);
}

// ---------- one-time W1 swizzle into MFMA B-fragment order (bf16) ----------
__global__ void wswiz_kernel(const float* __restrict__ W, unsigned short* __restrict__ wsw) {
    int idx = blockIdx.x * blockDim.x + threadIdx.x;  // 0 .. 16383
    if (idx < NF * HID) {
        int j = idx & 7;
        int lane = (idx >> 3) & 63;
        int ntile = (idx >> 9) & 3;
        int kiter = idx >> 11;
        int k = kiter * 32 + (lane >> 4) * 8 + j;
        int n = ntile * 16 + (lane & 15);
        wsw[idx] = f2bf(W[k * HID + n]);
    }
}

// ---------- h' = dinv[row] * (x @ W1) via MFMA (bf16 in, fp32 acc, bf16 out) ----------
__launch_bounds__(256)
__global__ void gemm1_mfma(const float* __restrict__ x, const unsigned short* __restrict__ wsw,
                           const float* __restrict__ dinv, unsigned short* __restrict__ h) {
    int t = threadIdx.x;
    int lane = t & 63;
    int wave = t >> 6;
    int m = lane & 15;
    int quad = lane >> 4;
    int rowbase = blockIdx.x * 64 + wave * 16;

    int row = rowbase + m;
    if (row >= N_NODES) row = N_NODES - 1;

    const short8* wv = (const short8*)wsw;

    f32x4 acc[4] = {{0.f,0.f,0.f,0.f},{0.f,0.f,0.f,0.f},{0.f,0.f,0.f,0.f},{0.f,0.f,0.f,0.f}};

    const float* xrow = x + (size_t)row * NF;
#pragma unroll
    for (int kiter = 0; kiter < 8; ++kiter) {
        int k0 = kiter * 32 + quad * 8;
        float4 xa = *(const float4*)&xrow[k0];
        float4 xb = *(const float4*)&xrow[k0 + 4];
        short8 a;
        a[0] = (short)f2bf(xa.x); a[1] = (short)f2bf(xa.y);
        a[2] = (short)f2bf(xa.z); a[3] = (short)f2bf(xa.w);
        a[4] = (short)f2bf(xb.x); a[5] = (short)f2bf(xb.y);
        a[6] = (short)f2bf(xb.z); a[7] = (short)f2bf(xb.w);
#pragma unroll
        for (int nt = 0; nt < 4; ++nt) {
            short8 b = wv[(kiter * 4 + nt) * 64 + lane];
            acc[nt] = __builtin_amdgcn_mfma_f32_16x16x32_bf16(a, b, acc[nt], 0, 0, 0);
        }
    }

    float di[4];
#pragma unroll
    for (int r = 0; r < 4; ++r) {
        int orow = rowbase + quad * 4 + r;
        di[r] = (orow < N_NODES) ? dinv[orow] : 0.f;
    }

#pragma unroll
    for (int nt = 0; nt < 4; ++nt) {
#pragma unroll
        for (int r = 0; r < 4; ++r) {
            int orow = rowbase + quad * 4 + r;
            if (orow < N_NODES) {
                int ocol = nt * 16 + m;
                h[(size_t)orow * HID + ocol] = f2bf(di[r] * acc[nt][r]);
            }
        }
    }
}

// ---------- fused layer-1: per-bucket LDS accumulation from pbuf (no CSR) ----------
// One block per bucket. acc[dl][f] += w * h'[s][f] via ds_add_f32.
// Epilogue: agg = dinv[d]*(acc + h'[d]) + b1; ELU; z' = dinv[d]*(v @ W2)
__launch_bounds__(512)
__global__ void fused1_lds(const int2* __restrict__ pbuf, const unsigned int* __restrict__ base,
                           const unsigned short* __restrict__ h,
                           const float* __restrict__ dinv, const float* __restrict__ b1,
                           const float* __restrict__ W2, float* __restrict__ z) {
    __shared__ float acc[128 * ASTR];   // 33280 B

    int t = threadIdx.x;
    int lane = t & 63;
    int wave = t >> 6;          // 0..7
    int f8 = lane & 7;          // uint4 slot: features 8*f8 .. 8*f8+7
    int g = lane >> 3;          // edge group 0..7
    int bkt = blockIdx.x;
    int d0 = bkt << BSHIFT;

    for (int i = t; i < 128 * ASTR; i += 512) acc[i] = 0.f;
    __syncthreads();

    const uint4* h128 = (const uint4*)h;
    unsigned lo = base[bkt], hi = base[bkt + 1];

    for (unsigned sb = lo + ((unsigned)wave << 6); sb < hi; sb += 512) {
        int n = (int)(hi - sb); if (n > 64) n = 64;
        int2 e = (lane < n) ? pbuf[sb + lane] : make_int2(0, 0);
        int j = 0;
        for (; j + 32 <= n; j += 32) {
            uint4 hp[4]; float w[4]; int dl[4];
#pragma unroll
            for (int u = 0; u < 4; ++u) {
                int idx = j + u * 8 + g;
                int ex = __shfl(e.x, idx);
                w[u] = __int_as_float(__shfl(e.y, idx));
                dl[u] = (ex >> 17) & 127;
                hp[u] = h128[(size_t)(ex & 0x1FFFF) * 8 + f8];
            }
#pragma unroll
            for (int u = 0; u < 4; ++u) {
                float* a = &acc[dl[u] * ASTR + f8 * 8];
                atomicAdd(&a[0], w[u] * bfl(hp[u].x));
                atomicAdd(&a[1], w[u] * bfh(hp[u].x));
                atomicAdd(&a[2], w[u] * bfl(hp[u].y));
                atomicAdd(&a[3], w[u] * bfh(hp[u].y));
                atomicAdd(&a[4], w[u] * bfl(hp[u].z));
                atomicAdd(&a[5], w[u] * bfh(hp[u].z));
                atomicAdd(&a[6], w[u] * bfl(hp[u].w));
                atomicAdd(&a[7], w[u] * bfh(hp[u].w));
            }
        }
        for (; j + 8 <= n; j += 8) {
            int idx = j + g;
            int ex = __shfl(e.x, idx);
            float w = __int_as_float(__shfl(e.y, idx));
            int dl = (ex >> 17) & 127;
            uint4 hp = h128[(size_t)(ex & 0x1FFFF) * 8 + f8];
            float* a = &acc[dl * ASTR + f8 * 8];
            atomicAdd(&a[0], w * bfl(hp.x));
            atomicAdd(&a[1], w * bfh(hp.x));
            atomicAdd(&a[2], w * bfl(hp.y));
            atomicAdd(&a[3], w * bfh(hp.y));
            atomicAdd(&a[4], w * bfl(hp.z));
            atomicAdd(&a[5], w * bfh(hp.z));
            atomicAdd(&a[6], w * bfl(hp.w));
            atomicAdd(&a[7], w * bfh(hp.w));
        }
        int rem = n - j;
        if (rem > 0) {
            int idx = j + (g < rem ? g : 0);
            int ex = __shfl(e.x, idx);
            float w = __int_as_float(__shfl(e.y, idx));
            if (g < rem) {
                int dl = (ex >> 17) & 127;
                uint4 hp = h128[(size_t)(ex & 0x1FFFF) * 8 + f8];
                float* a = &acc[dl * ASTR + f8 * 8];
                atomicAdd(&a[0], w * bfl(hp.x));
                atomicAdd(&a[1], w * bfh(hp.x));
                atomicAdd(&a[2], w * bfl(hp.y));
                atomicAdd(&a[3], w * bfh(hp.y));
                atomicAdd(&a[4], w * bfl(hp.z));
                atomicAdd(&a[5], w * bfh(hp.z));
                atomicAdd(&a[6], w * bfl(hp.w));
                atomicAdd(&a[7], w * bfh(hp.w));
            }
        }
    }
    __syncthreads();

    // epilogue: 8 lanes per dst; threads 0..511 cover dl = t>>3 and (t>>3)+64
    for (int dl = t >> 3; dl < 128; dl += 64) {
        int d = d0 + dl;
        if (d < N_NODES) {
            float di = dinv[d];
            uint4 hd = h128[(size_t)d * 8 + f8];
            float4 bLo = *(const float4*)&b1[8 * f8];
            float4 bHi = *(const float4*)&b1[8 * f8 + 4];
            float4 wLo = *(const float4*)&W2[8 * f8];
            float4 wHi = *(const float4*)&W2[8 * f8 + 4];
            const float* a = &acc[dl * ASTR + f8 * 8];

            float v0 = di * (a[0] + bfl(hd.x)) + bLo.x;
            float v1 = di * (a[1] + bfh(hd.x)) + bLo.y;
            float v2 = di * (a[2] + bfl(hd.y)) + bLo.z;
            float v3 = di * (a[3] + bfh(hd.y)) + bLo.w;
            float v4 = di * (a[4] + bfl(hd.z)) + bHi.x;
            float v5 = di * (a[5] + bfh(hd.z)) + bHi.y;
            float v6 = di * (a[6] + bfl(hd.w)) + bHi.z;
            float v7 = di * (a[7] + bfh(hd.w)) + bHi.w;
            v0 = (v0 > 0.f) ? v0 : (__expf(v0) - 1.f);
            v1 = (v1 > 0.f) ? v1 : (__expf(v1) - 1.f);
            v2 = (v2 > 0.f) ? v2 : (__expf(v2) - 1.f);
            v3 = (v3 > 0.f) ? v3 : (__expf(v3) - 1.f);
            v4 = (v4 > 0.f) ? v4 : (__expf(v4) - 1.f);
            v5 = (v5 > 0.f) ? v5 : (__expf(v5) - 1.f);
            v6 = (v6 > 0.f) ? v6 : (__expf(v6) - 1.f);
            v7 = (v7 > 0.f) ? v7 : (__expf(v7) - 1.f);

            float p = v0 * wLo.x + v1 * wLo.y + v2 * wLo.z + v3 * wLo.w
                    + v4 * wHi.x + v5 * wHi.y + v6 * wHi.z + v7 * wHi.w;
            p += __shfl_down(p, 4);
            p += __shfl_down(p, 2);
            p += __shfl_down(p, 1);
            if (f8 == 0) z[d] = di * p;   // z' = dinv[d] * z
        }
    }
}

// ---------- fused layer-2: per-bucket LDS accumulation from pbuf ----------
// v = dinv[d]*(sum_e ew*z'[s] + z'[d]) + b2; out = sigmoid(v)
__launch_bounds__(256)
__global__ void fused2_lds(const int2* __restrict__ pbuf, const unsigned int* __restrict__ base,
                           const float* __restrict__ z, const float* __restrict__ dinv,
                           const float* __restrict__ b2, float* __restrict__ out) {
    __shared__ float acc2[128];
    int t = threadIdx.x;
    int bkt = blockIdx.x;
    if (t < 128) acc2[t] = 0.f;
    __syncthreads();
    unsigned lo = base[bkt], hi = base[bkt + 1];
    for (unsigned i = lo + t; i < hi; i += 256) {
        int2 e = pbuf[i];
        atomicAdd(&acc2[(e.x >> 17) & 127], __int_as_float(e.y) * z[e.x & 0x1FFFF]);
    }
    __syncthreads();
    int d0 = bkt << BSHIFT;
    if (t < 128 && d0 + t < N_NODES) {
        float di = dinv[d0 + t];
        float v = di * (acc2[t] + z[d0 + t]) + b2[0];
        out[d0 + t] = 1.0f / (1.0f + __expf(-v));
    }
}

extern "C" void kernel_launch(void* const* d_in, const int* in_sizes, int n_in,
                              void* d_out, int out_size, void* d_ws, size_t ws_size,
                              hipStream_t stream) {
    const float* x  = (const float*)d_in[0];
    const int*   ei = (const int*)d_in[1];
    const float* ew = (const float*)d_in[2];
    const float* W1 = (const float*)d_in[3];
    const float* b1 = (const float*)d_in[4];
    const float* W2 = (const float*)d_in[5];
    const float* b2 = (const float*)d_in[6];
    float* out = (float*)d_out;

    char* ws = (char*)d_ws;
    unsigned int* blkhist = (unsigned int*)ws;                  ws += (size_t)NP1 * NBUCK * 4;
    unsigned int* blkbase = (unsigned int*)ws;                  ws += (size_t)NBUCK * NP1 * 4;
    unsigned int* total   = (unsigned int*)ws;                  ws += (size_t)NBUCK * 4;
    unsigned int* base    = (unsigned int*)ws;                  ws += (size_t)(NBUCK + 1) * 4;
    float* dinv    = (float*)ws;                                ws += (size_t)N_NODES * 4;
    int2*  pbuf    = (int2*)ws;                                 ws += (size_t)N_EDGES * 8;
    unsigned short* h = (unsigned short*)ws;                    ws += (size_t)N_NODES * HID * 2;
    unsigned short* wsw = (unsigned short*)ws;                  ws += (size_t)NF * HID * 2;
    float* z       = (float*)ws;                                ws += (size_t)N_NODES * 4;

    p1count<<<NP1, 256, 0, stream>>>(ei, blkhist);
    bktAC<<<(NBUCK + TB - 1) / TB, 256, 0, stream>>>(blkhist, total, blkbase);
    bktB<<<1, 1024, 0, stream>>>(total, base);
    p1scatter<<<NP1, 256, 0, stream>>>(ei, ew, blkhist, base, blkbase, pbuf);
    p2deg<<<NBUCK, 256, 0, stream>>>(pbuf, base, dinv);

    wswiz_kernel<<<(NF * HID + 255) / 256, 256, 0, stream>>>(W1, wsw);
    gemm1_mfma<<<(N_NODES + 63) / 64, 256, 0, stream>>>(x, wsw, dinv, h);

    fused1_lds<<<NBUCK, 512, 0, stream>>>(pbuf, base, h, dinv, b1, W2, z);
    fused2_lds<<<NBUCK, 256, 0, stream>>>(pbuf, base, z, dinv, b2, out);
}

// Round 7
// 421.474 us; speedup vs baseline: 3.9079x; 3.9079x over previous
//
#include <hip/hip_runtime.h>

#define N_NODES 100000
#define N_EDGES 3200000
#define NF 256
#define HID 64
#define BSHIFT 7
#define NBUCK 782                       // ceil(100000 / 128)
#define NP1 512                         // phase-1 partition blocks
#define CHUNKE (N_EDGES / NP1)          // 6250 exactly
#define MAXB 5120                       // LDS sort capacity per bucket (mean 4096, ~16 sigma)

typedef short short8 __attribute__((ext_vector_type(8)));
typedef float f32x4 __attribute__((ext_vector_type(4)));

__device__ __forceinline__ unsigned short f2bf(float v) {
    unsigned int u = __float_as_uint(v);
    u += 0x7FFFu + ((u >> 16) & 1u);
    return (unsigned short)(u >> 16);
}
__device__ __forceinline__ float bfl(unsigned int p) { return __uint_as_float((p & 0xFFFFu) << 16); }
__device__ __forceinline__ float bfh(unsigned int p) { return __uint_as_float(p & 0xFFFF0000u); }

// ---------- 1a: per-block LDS histogram -> blkhist[block][bucket] ----------
__launch_bounds__(256)
__global__ void p1count(const int* __restrict__ ei, unsigned int* __restrict__ blkhist) {
    __shared__ unsigned int hist[NBUCK];
    for (int i = threadIdx.x; i < NBUCK; i += 256) hist[i] = 0;
    __syncthreads();
    int lo = blockIdx.x * CHUNKE;
    int hi = lo + CHUNKE;
    for (int e = lo + threadIdx.x; e < hi; e += 256)
        atomicAdd(&hist[((unsigned)ei[N_EDGES + e]) >> BSHIFT], 1u);
    __syncthreads();
    unsigned int* row = blkhist + (size_t)blockIdx.x * NBUCK;
    for (int i = threadIdx.x; i < NBUCK; i += 256) row[i] = hist[i];
}

// ---------- 1b: column reduce -> bucket_total[bucket] ----------
__launch_bounds__(256)
__global__ void bktA(const unsigned int* __restrict__ blkhist, unsigned int* __restrict__ total) {
    __shared__ unsigned int sh[256];
    int i = blockIdx.x;              // bucket
    int t = threadIdx.x;
    unsigned s = 0;
    for (int b = t; b < NP1; b += 256) s += blkhist[(size_t)b * NBUCK + i];
    sh[t] = s;
    __syncthreads();
    for (int off = 128; off > 0; off >>= 1) {
        if (t < off) sh[t] += sh[t + off];
        __syncthreads();
    }
    if (t == 0) total[i] = sh[0];
}

// ---------- 1c: exclusive scan of bucket totals -> bucket_base ----------
__launch_bounds__(1024)
__global__ void bktB(const unsigned int* __restrict__ total, unsigned int* __restrict__ base) {
    __shared__ unsigned int sh[1024];
    int t = threadIdx.x;
    unsigned v = (t < NBUCK) ? total[t] : 0;
    sh[t] = v;
    __syncthreads();
    for (int off = 1; off < 1024; off <<= 1) {
        unsigned a = (t >= off) ? sh[t - off] : 0;
        __syncthreads();
        sh[t] += a;
        __syncthreads();
    }
    if (t < NBUCK) base[t] = sh[t] - v;
    if (t == 0) base[NBUCK] = N_EDGES;
}

// ---------- 1d: per-bucket scan across blocks -> blkbase[bucket][block] (absolute) ----------
__launch_bounds__(256)
__global__ void bktC(const unsigned int* __restrict__ blkhist, const unsigned int* __restrict__ base,
                     unsigned int* __restrict__ blkbase) {
    __shared__ unsigned int sh[256];
    int i = blockIdx.x;              // bucket
    int t = threadIdx.x;
    unsigned c[2];
    unsigned s = 0;
#pragma unroll
    for (int j = 0; j < 2; ++j) {
        c[j] = blkhist[(size_t)(2 * t + j) * NBUCK + i];
        s += c[j];
    }
    sh[t] = s;
    __syncthreads();
    for (int off = 1; off < 256; off <<= 1) {
        unsigned a = (t >= off) ? sh[t - off] : 0;
        __syncthreads();
        sh[t] += a;
        __syncthreads();
    }
    unsigned run = base[i] + sh[t] - s;
    unsigned int* orow = blkbase + (size_t)i * NP1 + 2 * t;
    orow[0] = run; run += c[0];
    orow[1] = run;
}

// ---------- 1e: staged scatter — LDS counting sort, then coalesced run write-out ----------
// pbuf entry: x = src | (dst_low7 << 17), y = ew bits
__launch_bounds__(256)
__global__ void p1scatter(const int* __restrict__ ei, const float* __restrict__ ew,
                          const unsigned int* __restrict__ blkhist,
                          const unsigned int* __restrict__ blkbase, int2* __restrict__ pbuf) {
    __shared__ int2 sorted[CHUNKE];           // 50000 B
    __shared__ unsigned int loff[NBUCK + 2];
    __shared__ unsigned int cur[NBUCK];
    __shared__ unsigned int sh[256];

    int t = threadIdx.x;
    int b = blockIdx.x;

    unsigned u[4];
    unsigned s = 0;
#pragma unroll
    for (int j = 0; j < 4; ++j) {
        int idx = 4 * t + j;
        u[j] = (idx < NBUCK) ? blkhist[(size_t)b * NBUCK + idx] : 0u;
        s += u[j];
    }
    sh[t] = s;
    __syncthreads();
    for (int off = 1; off < 256; off <<= 1) {
        unsigned a = (t >= off) ? sh[t - off] : 0;
        __syncthreads();
        sh[t] += a;
        __syncthreads();
    }
    unsigned run = sh[t] - s;
#pragma unroll
    for (int j = 0; j < 4; ++j) {
        int idx = 4 * t + j;
        if (idx <= NBUCK) loff[idx] = run;
        run += u[j];
        if (idx < NBUCK) cur[idx] = 0;
    }
    __syncthreads();

    int lo = b * CHUNKE;
    int hi = lo + CHUNKE;
    for (int e = lo + t; e < hi; e += 256) {
        int src = ei[e];
        unsigned d = (unsigned)ei[N_EDGES + e];
        unsigned k = d >> BSHIFT;
        unsigned r = atomicAdd(&cur[k], 1u);
        sorted[loff[k] + r] = make_int2(src | (int)((d & 127u) << 17), __float_as_int(ew[e]));
    }
    __syncthreads();

    int lane = t & 63;
    int wave = t >> 6;
    int q = lane >> 3;
    int r8 = lane & 7;
    for (int k0 = wave * 8; k0 < NBUCK; k0 += 32) {
        int k = k0 + q;
        if (k < NBUCK) {
            unsigned off = loff[k];
            int n = (int)(loff[k + 1] - off);
            unsigned gb = blkbase[(size_t)k * NP1 + b];
            for (int i = r8; i < n; i += 8)
                pbuf[gb + i] = sorted[off + i];
        }
    }
}

// ---------- phase 2: weighted degree + dinv only ----------
__launch_bounds__(256)
__global__ void p2deg(const int2* __restrict__ pbuf, const unsigned int* __restrict__ base,
                      float* __restrict__ dinv) {
    __shared__ float ldeg[128];
    int t = threadIdx.x;
    int bkt = blockIdx.x;
    if (t < 128) ldeg[t] = 0.f;
    __syncthreads();
    unsigned lo = base[bkt], hi = base[bkt + 1];
    for (unsigned i = lo + t; i < hi; i += 256) {
        int2 e = pbuf[i];
        atomicAdd(&ldeg[(e.x >> 17) & 127], __int_as_float(e.y));
    }
    __syncthreads();
    int d0 = bkt << BSHIFT;
    if (t < 128 && d0 + t < N_NODES) dinv[d0 + t] = rsqrtf(ldeg[t] + 1.0f);
}

// ---------- one-time W1 swizzle into MFMA B-fragment order (bf16) ----------
__global__ void wswiz_kernel(const float* __restrict__ W, unsigned short* __restrict__ wsw) {
    int idx = blockIdx.x * blockDim.x + threadIdx.x;  // 0 .. 16383
    if (idx < NF * HID) {
        int j = idx & 7;
        int lane = (idx >> 3) & 63;
        int ntile = (idx >> 9) & 3;
        int kiter = idx >> 11;
        int k = kiter * 32 + (lane >> 4) * 8 + j;
        int n = ntile * 16 + (lane & 15);
        wsw[idx] = f2bf(W[k * HID + n]);
    }
}

// ---------- h' = dinv[row] * (x @ W1) via MFMA ----------
__launch_bounds__(256)
__global__ void gemm1_mfma(const float* __restrict__ x, const unsigned short* __restrict__ wsw,
                           const float* __restrict__ dinv, unsigned short* __restrict__ h) {
    int t = threadIdx.x;
    int lane = t & 63;
    int wave = t >> 6;
    int m = lane & 15;
    int quad = lane >> 4;
    int rowbase = blockIdx.x * 64 + wave * 16;

    int row = rowbase + m;
    if (row >= N_NODES) row = N_NODES - 1;

    const short8* wv = (const short8*)wsw;

    f32x4 acc[4] = {{0.f,0.f,0.f,0.f},{0.f,0.f,0.f,0.f},{0.f,0.f,0.f,0.f},{0.f,0.f,0.f,0.f}};

    const float* xrow = x + (size_t)row * NF;
#pragma unroll
    for (int kiter = 0; kiter < 8; ++kiter) {
        int k0 = kiter * 32 + quad * 8;
        float4 xa = *(const float4*)&xrow[k0];
        float4 xb = *(const float4*)&xrow[k0 + 4];
        short8 a;
        a[0] = (short)f2bf(xa.x); a[1] = (short)f2bf(xa.y);
        a[2] = (short)f2bf(xa.z); a[3] = (short)f2bf(xa.w);
        a[4] = (short)f2bf(xb.x); a[5] = (short)f2bf(xb.y);
        a[6] = (short)f2bf(xb.z); a[7] = (short)f2bf(xb.w);
#pragma unroll
        for (int nt = 0; nt < 4; ++nt) {
            short8 b = wv[(kiter * 4 + nt) * 64 + lane];
            acc[nt] = __builtin_amdgcn_mfma_f32_16x16x32_bf16(a, b, acc[nt], 0, 0, 0);
        }
    }

    float di[4];
#pragma unroll
    for (int r = 0; r < 4; ++r) {
        int orow = rowbase + quad * 4 + r;
        di[r] = (orow < N_NODES) ? dinv[orow] : 0.f;
    }

#pragma unroll
    for (int nt = 0; nt < 4; ++nt) {
#pragma unroll
        for (int r = 0; r < 4; ++r) {
            int orow = rowbase + quad * 4 + r;
            if (orow < N_NODES) {
                int ocol = nt * 16 + m;
                h[(size_t)orow * HID + ocol] = f2bf(di[r] * acc[nt][r]);
            }
        }
    }
}

// ---------- fused layer-1: in-kernel dst-sort (LDS) + register-FMA aggregation ----------
// One block (512 thr) per bucket. Sort 4096 edges into LDS runs (3 LDS ops/edge),
// then each wave aggregates dst runs with the proven 16-lane x uint2 gather.
// agg = dinv[d]*(sum ew*h'[s] + h'[d]) + b1; ELU; z' = dinv[d]*(v @ W2)
__launch_bounds__(512)
__global__ void fused1s(const int2* __restrict__ pbuf, const unsigned int* __restrict__ base,
                        const unsigned short* __restrict__ h,
                        const float* __restrict__ dinv, const float* __restrict__ b1,
                        const float* __restrict__ W2, float* __restrict__ z) {
    __shared__ int2 sorted[MAXB];      // 40960 B
    __shared__ int lcnt[128];
    __shared__ int loff[128];
    __shared__ int sc[128];
    __shared__ unsigned int lcur[128];

    int t = threadIdx.x;
    int bkt = blockIdx.x;
    unsigned b0 = base[bkt], bh = base[bkt + 1];
    int nb = (int)(bh - b0);
    int d0 = bkt << BSHIFT;

    bool use_sort = (nb <= MAXB);      // block-uniform
    if (use_sort) {
        if (t < 128) { lcnt[t] = 0; lcur[t] = 0; }
        __syncthreads();
        // count
        for (int i = t; i < nb; i += 512) {
            int2 e = pbuf[b0 + i];
            atomicAdd(&lcnt[(e.x >> 17) & 127], 1);
        }
        __syncthreads();
        // exclusive scan of counts (first 128 threads)
        int c = (t < 128) ? lcnt[t] : 0;
        if (t < 128) sc[t] = c;
        __syncthreads();
        for (int off = 1; off < 128; off <<= 1) {
            int a = (t < 128 && t >= off) ? sc[t - off] : 0;
            __syncthreads();
            if (t < 128) sc[t] += a;
            __syncthreads();
        }
        if (t < 128) loff[t] = sc[t] - c;
        __syncthreads();
        // placement
        for (int i = t; i < nb; i += 512) {
            int2 e = pbuf[b0 + i];
            int dl = (e.x >> 17) & 127;
            unsigned r = atomicAdd(&lcur[dl], 1u);
            sorted[loff[dl] + (int)r] = e;
        }
        __syncthreads();
    }

    int lane = t & 63;
    int wave = t >> 6;          // 0..7
    int f = lane & 15;
    int g = lane >> 4;
    const uint2* h64 = (const uint2*)h;

    for (int dl = wave; dl < 128; dl += 8) {
        int d = d0 + dl;
        if (d >= N_NODES) break;     // monotone in dl, wave-uniform

        float4 acc = make_float4(0.f, 0.f, 0.f, 0.f);

        if (use_sort) {
            int start = loff[dl];
            int end = start + lcnt[dl];
            int i = start + g;
            for (; i + 12 < end; i += 16) {
                int2 e0 = sorted[i];
                int2 e1 = sorted[i + 4];
                int2 e2 = sorted[i + 8];
                int2 e3 = sorted[i + 12];
                uint2 h0 = h64[(size_t)(e0.x & 0x1FFFF) * 16 + f];
                uint2 h1 = h64[(size_t)(e1.x & 0x1FFFF) * 16 + f];
                uint2 h2 = h64[(size_t)(e2.x & 0x1FFFF) * 16 + f];
                uint2 h3 = h64[(size_t)(e3.x & 0x1FFFF) * 16 + f];
                float w0 = __int_as_float(e0.y), w1 = __int_as_float(e1.y);
                float w2 = __int_as_float(e2.y), w3 = __int_as_float(e3.y);
                acc.x = fmaf(w0, bfl(h0.x), acc.x); acc.y = fmaf(w0, bfh(h0.x), acc.y);
                acc.z = fmaf(w0, bfl(h0.y), acc.z); acc.w = fmaf(w0, bfh(h0.y), acc.w);
                acc.x = fmaf(w1, bfl(h1.x), acc.x); acc.y = fmaf(w1, bfh(h1.x), acc.y);
                acc.z = fmaf(w1, bfl(h1.y), acc.z); acc.w = fmaf(w1, bfh(h1.y), acc.w);
                acc.x = fmaf(w2, bfl(h2.x), acc.x); acc.y = fmaf(w2, bfh(h2.x), acc.y);
                acc.z = fmaf(w2, bfl(h2.y), acc.z); acc.w = fmaf(w2, bfh(h2.y), acc.w);
                acc.x = fmaf(w3, bfl(h3.x), acc.x); acc.y = fmaf(w3, bfh(h3.x), acc.y);
                acc.z = fmaf(w3, bfl(h3.y), acc.z); acc.w = fmaf(w3, bfh(h3.y), acc.w);
            }
            for (; i < end; i += 4) {
                int2 e = sorted[i];
                float w = __int_as_float(e.y);
                uint2 hp = h64[(size_t)(e.x & 0x1FFFF) * 16 + f];
                acc.x = fmaf(w, bfl(hp.x), acc.x); acc.y = fmaf(w, bfh(hp.x), acc.y);
                acc.z = fmaf(w, bfl(hp.y), acc.z); acc.w = fmaf(w, bfh(hp.y), acc.w);
            }
        } else {
            // fallback (statistically unreachable): scan whole bucket from global
            for (int i = g; i < nb; i += 4) {
                int2 e = pbuf[b0 + i];
                if (((e.x >> 17) & 127) == dl) {
                    float w = __int_as_float(e.y);
                    uint2 hp = h64[(size_t)(e.x & 0x1FFFF) * 16 + f];
                    acc.x = fmaf(w, bfl(hp.x), acc.x); acc.y = fmaf(w, bfh(hp.x), acc.y);
                    acc.z = fmaf(w, bfl(hp.y), acc.z); acc.w = fmaf(w, bfh(hp.y), acc.w);
                }
            }
        }

        // reduce over the 4 edge-groups (stride-16 lanes)
        acc.x += __shfl_down(acc.x, 32); acc.y += __shfl_down(acc.y, 32);
        acc.z += __shfl_down(acc.z, 32); acc.w += __shfl_down(acc.w, 32);
        acc.x += __shfl_down(acc.x, 16); acc.y += __shfl_down(acc.y, 16);
        acc.z += __shfl_down(acc.z, 16); acc.w += __shfl_down(acc.w, 16);

        float di = dinv[d];
        uint2 hd = h64[(size_t)d * 16 + f];   // h' already carries dinv[d]
        float4 b = *(const float4*)&b1[4 * f];
        float4 w2 = *(const float4*)&W2[4 * f];

        float v0 = di * (acc.x + bfl(hd.x)) + b.x;
        float v1 = di * (acc.y + bfh(hd.x)) + b.y;
        float v2 = di * (acc.z + bfl(hd.y)) + b.z;
        float v3 = di * (acc.w + bfh(hd.y)) + b.w;
        v0 = (v0 > 0.f) ? v0 : (__expf(v0) - 1.f);
        v1 = (v1 > 0.f) ? v1 : (__expf(v1) - 1.f);
        v2 = (v2 > 0.f) ? v2 : (__expf(v2) - 1.f);
        v3 = (v3 > 0.f) ? v3 : (__expf(v3) - 1.f);

        float p = v0 * w2.x + v1 * w2.y + v2 * w2.z + v3 * w2.w;
        p += __shfl_down(p, 8);
        p += __shfl_down(p, 4);
        p += __shfl_down(p, 2);
        p += __shfl_down(p, 1);
        if (lane == 0) z[d] = di * p;        // z' = dinv[d] * z
    }
}

// ---------- fused layer-2: per-bucket LDS accumulation from pbuf (1 atomic/edge) ----------
// v = dinv[d]*(sum_e ew*z'[s] + z'[d]) + b2; out = sigmoid(v)
__launch_bounds__(256)
__global__ void fused2_lds(const int2* __restrict__ pbuf, const unsigned int* __restrict__ base,
                           const float* __restrict__ z, const float* __restrict__ dinv,
                           const float* __restrict__ b2, float* __restrict__ out) {
    __shared__ float acc2[128];
    int t = threadIdx.x;
    int bkt = blockIdx.x;
    if (t < 128) acc2[t] = 0.f;
    __syncthreads();
    unsigned lo = base[bkt], hi = base[bkt + 1];
    for (unsigned i = lo + t; i < hi; i += 256) {
        int2 e = pbuf[i];
        atomicAdd(&acc2[(e.x >> 17) & 127], __int_as_float(e.y) * z[e.x & 0x1FFFF]);
    }
    __syncthreads();
    int d0 = bkt << BSHIFT;
    if (t < 128 && d0 + t < N_NODES) {
        float di = dinv[d0 + t];
        float v = di * (acc2[t] + z[d0 + t]) + b2[0];
        out[d0 + t] = 1.0f / (1.0f + __expf(-v));
    }
}

extern "C" void kernel_launch(void* const* d_in, const int* in_sizes, int n_in,
                              void* d_out, int out_size, void* d_ws, size_t ws_size,
                              hipStream_t stream) {
    const float* x  = (const float*)d_in[0];
    const int*   ei = (const int*)d_in[1];
    const float* ew = (const float*)d_in[2];
    const float* W1 = (const float*)d_in[3];
    const float* b1 = (const float*)d_in[4];
    const float* W2 = (const float*)d_in[5];
    const float* b2 = (const float*)d_in[6];
    float* out = (float*)d_out;

    char* ws = (char*)d_ws;
    unsigned int* blkhist = (unsigned int*)ws;                  ws += (size_t)NP1 * NBUCK * 4;
    unsigned int* blkbase = (unsigned int*)ws;                  ws += (size_t)NBUCK * NP1 * 4;
    unsigned int* total   = (unsigned int*)ws;                  ws += (size_t)NBUCK * 4;
    unsigned int* base    = (unsigned int*)ws;                  ws += (size_t)(NBUCK + 1) * 4;
    float* dinv    = (float*)ws;                                ws += (size_t)N_NODES * 4;
    int2*  pbuf    = (int2*)ws;                                 ws += (size_t)N_EDGES * 8;
    unsigned short* h = (unsigned short*)ws;                    ws += (size_t)N_NODES * HID * 2;
    unsigned short* wsw = (unsigned short*)ws;                  ws += (size_t)NF * HID * 2;
    float* z       = (float*)ws;                                ws += (size_t)N_NODES * 4;

    p1count<<<NP1, 256, 0, stream>>>(ei, blkhist);
    bktA<<<NBUCK, 256, 0, stream>>>(blkhist, total);
    bktB<<<1, 1024, 0, stream>>>(total, base);
    bktC<<<NBUCK, 256, 0, stream>>>(blkhist, base, blkbase);
    p1scatter<<<NP1, 256, 0, stream>>>(ei, ew, blkhist, blkbase, pbuf);
    p2deg<<<NBUCK, 256, 0, stream>>>(pbuf, base, dinv);

    wswiz_kernel<<<(NF * HID + 255) / 256, 256, 0, stream>>>(W1, wsw);
    gemm1_mfma<<<(N_NODES + 63) / 64, 256, 0, stream>>>(x, wsw, dinv, h);

    fused1s<<<NBUCK, 512, 0, stream>>>(pbuf, base, h, dinv, b1, W2, z);
    fused2_lds<<<NBUCK, 256, 0, stream>>>(pbuf, base, z, dinv, b2, out);
}

// Round 8
// 397.068 us; speedup vs baseline: 4.1481x; 1.0615x over previous
//
#include <hip/hip_runtime.h>

#define N_NODES 100000
#define N_EDGES 3200000
#define NF 256
#define HID 64
#define BSHIFT 7
#define NBUCK 782                       // ceil(100000 / 128)
#define NP1 512                         // phase-1 partition blocks
#define CHUNKE (N_EDGES / NP1)          // 6250 exactly (even)
#define MAXB 5120                       // p2ab LDS sort capacity per bucket (mean 4096, ~16 sigma)
#define NQ 25000                        // dsts per fused1 quarter

typedef short short8 __attribute__((ext_vector_type(8)));
typedef float f32x4 __attribute__((ext_vector_type(4)));

__device__ __forceinline__ unsigned short f2bf(float v) {
    unsigned int u = __float_as_uint(v);
    u += 0x7FFFu + ((u >> 16) & 1u);
    return (unsigned short)(u >> 16);
}
__device__ __forceinline__ float bfl(unsigned int p) { return __uint_as_float((p & 0xFFFFu) << 16); }
__device__ __forceinline__ float bfh(unsigned int p) { return __uint_as_float(p & 0xFFFF0000u); }

// ---------- 1a: per-block LDS histogram -> blkhist[block][bucket] (int2 edge loads) ----------
__launch_bounds__(256)
__global__ void p1count(const int* __restrict__ ei, unsigned int* __restrict__ blkhist) {
    __shared__ unsigned int hist[NBUCK];
    for (int i = threadIdx.x; i < NBUCK; i += 256) hist[i] = 0;
    __syncthreads();
    int lo = blockIdx.x * CHUNKE;
    int hi = lo + CHUNKE;
    for (int e = lo + 2 * threadIdx.x; e < hi; e += 512) {
        int2 d2 = *(const int2*)&ei[N_EDGES + e];
        atomicAdd(&hist[((unsigned)d2.x) >> BSHIFT], 1u);
        atomicAdd(&hist[((unsigned)d2.y) >> BSHIFT], 1u);
    }
    __syncthreads();
    unsigned int* row = blkhist + (size_t)blockIdx.x * NBUCK;
    for (int i = threadIdx.x; i < NBUCK; i += 256) row[i] = hist[i];
}

// ---------- 1b: column reduce -> bucket_total[bucket] ----------
__launch_bounds__(256)
__global__ void bktA(const unsigned int* __restrict__ blkhist, unsigned int* __restrict__ total) {
    __shared__ unsigned int sh[256];
    int i = blockIdx.x;              // bucket
    int t = threadIdx.x;
    unsigned s = 0;
    for (int b = t; b < NP1; b += 256) s += blkhist[(size_t)b * NBUCK + i];
    sh[t] = s;
    __syncthreads();
    for (int off = 128; off > 0; off >>= 1) {
        if (t < off) sh[t] += sh[t + off];
        __syncthreads();
    }
    if (t == 0) total[i] = sh[0];
}

// ---------- 1c: exclusive scan of bucket totals -> bucket_base ----------
__launch_bounds__(1024)
__global__ void bktB(const unsigned int* __restrict__ total, unsigned int* __restrict__ base) {
    __shared__ unsigned int sh[1024];
    int t = threadIdx.x;
    unsigned v = (t < NBUCK) ? total[t] : 0;
    sh[t] = v;
    __syncthreads();
    for (int off = 1; off < 1024; off <<= 1) {
        unsigned a = (t >= off) ? sh[t - off] : 0;
        __syncthreads();
        sh[t] += a;
        __syncthreads();
    }
    if (t < NBUCK) base[t] = sh[t] - v;
    if (t == 0) base[NBUCK] = N_EDGES;
}

// ---------- 1d: per-bucket scan across blocks -> blkbase[bucket][block] (absolute) ----------
__launch_bounds__(256)
__global__ void bktC(const unsigned int* __restrict__ blkhist, const unsigned int* __restrict__ base,
                     unsigned int* __restrict__ blkbase) {
    __shared__ unsigned int sh[256];
    int i = blockIdx.x;              // bucket
    int t = threadIdx.x;
    unsigned c[2];
    unsigned s = 0;
#pragma unroll
    for (int j = 0; j < 2; ++j) {
        c[j] = blkhist[(size_t)(2 * t + j) * NBUCK + i];
        s += c[j];
    }
    sh[t] = s;
    __syncthreads();
    for (int off = 1; off < 256; off <<= 1) {
        unsigned a = (t >= off) ? sh[t - off] : 0;
        __syncthreads();
        sh[t] += a;
        __syncthreads();
    }
    unsigned run = base[i] + sh[t] - s;
    unsigned int* orow = blkbase + (size_t)i * NP1 + 2 * t;
    orow[0] = run; run += c[0];
    orow[1] = run;
}

// ---------- 1e: staged scatter — LDS counting sort, then coalesced run write-out ----------
// pbuf entry: x = src | (dst_low7 << 17), y = ew bits.  int2/float2 edge loads.
__launch_bounds__(256)
__global__ void p1scatter(const int* __restrict__ ei, const float* __restrict__ ew,
                          const unsigned int* __restrict__ blkhist,
                          const unsigned int* __restrict__ blkbase, int2* __restrict__ pbuf) {
    __shared__ int2 sorted[CHUNKE];           // 50000 B
    __shared__ unsigned int loff[NBUCK + 2];
    __shared__ unsigned int cur[NBUCK];
    __shared__ unsigned int sh[256];

    int t = threadIdx.x;
    int b = blockIdx.x;

    unsigned u[4];
    unsigned s = 0;
#pragma unroll
    for (int j = 0; j < 4; ++j) {
        int idx = 4 * t + j;
        u[j] = (idx < NBUCK) ? blkhist[(size_t)b * NBUCK + idx] : 0u;
        s += u[j];
    }
    sh[t] = s;
    __syncthreads();
    for (int off = 1; off < 256; off <<= 1) {
        unsigned a = (t >= off) ? sh[t - off] : 0;
        __syncthreads();
        sh[t] += a;
        __syncthreads();
    }
    unsigned run = sh[t] - s;
#pragma unroll
    for (int j = 0; j < 4; ++j) {
        int idx = 4 * t + j;
        if (idx <= NBUCK) loff[idx] = run;
        run += u[j];
        if (idx < NBUCK) cur[idx] = 0;
    }
    __syncthreads();

    int lo = b * CHUNKE;
    int hi = lo + CHUNKE;
    for (int e = lo + 2 * t; e < hi; e += 512) {
        int2 s2 = *(const int2*)&ei[e];
        int2 d2 = *(const int2*)&ei[N_EDGES + e];
        float2 w2 = *(const float2*)&ew[e];
        unsigned k0 = ((unsigned)d2.x) >> BSHIFT;
        unsigned r0 = atomicAdd(&cur[k0], 1u);
        sorted[loff[k0] + r0] = make_int2(s2.x | (int)(((unsigned)d2.x & 127u) << 17), __float_as_int(w2.x));
        unsigned k1 = ((unsigned)d2.y) >> BSHIFT;
        unsigned r1 = atomicAdd(&cur[k1], 1u);
        sorted[loff[k1] + r1] = make_int2(s2.y | (int)(((unsigned)d2.y & 127u) << 17), __float_as_int(w2.y));
    }
    __syncthreads();

    int lane = t & 63;
    int wave = t >> 6;
    int q = lane >> 3;
    int r8 = lane & 7;
    for (int k0 = wave * 8; k0 < NBUCK; k0 += 32) {
        int k = k0 + q;
        if (k < NBUCK) {
            unsigned off = loff[k];
            int n = (int)(loff[k + 1] - off);
            unsigned gb = blkbase[(size_t)k * NP1 + b];
            for (int i = r8; i < n; i += 8)
                pbuf[gb + i] = sorted[off + i];
        }
    }
}

// ---------- phase 2 (merged): cnt + weighted deg + dinv + scan + LDS sort + coalesced CSR ----------
// ebuf stores RAW edge weight; dinv[s]/dinv[d] are folded into h' and z' downstream.
__launch_bounds__(256)
__global__ void p2ab(const int2* __restrict__ pbuf, const unsigned int* __restrict__ base,
                     float* __restrict__ dinv, int* __restrict__ row_ptr,
                     int2* __restrict__ ebuf) {
    __shared__ int lcnt[128];
    __shared__ float ldeg[128];
    __shared__ int sc[128];
    __shared__ int loff[128];
    __shared__ unsigned int lcur[128];
    __shared__ int2 sorted[MAXB];    // 40 KB

    int t = threadIdx.x;
    int bkt = blockIdx.x;
    unsigned b0 = base[bkt], bh = base[bkt + 1];
    int nb = (int)(bh - b0);
    int d0 = bkt << BSHIFT;
    int nd = N_NODES - d0; if (nd > 128) nd = 128;

    if (t < 128) { lcnt[t] = 0; ldeg[t] = 0.f; lcur[t] = 0; }
    __syncthreads();

    // pass 1: per-dst counts + weighted degree
    for (int i = t; i < nb; i += 256) {
        int2 e = pbuf[b0 + i];
        int dl = (e.x >> 17) & 127;
        atomicAdd(&lcnt[dl], 1);
        atomicAdd(&ldeg[dl], __int_as_float(e.y));
    }
    __syncthreads();

    // inclusive scan over 128 counts
    int c = (t < 128) ? lcnt[t] : 0;
    if (t < 128) sc[t] = c;
    __syncthreads();
    for (int off = 1; off < 128; off <<= 1) {
        int a = (t < 128 && t >= off) ? sc[t - off] : 0;
        __syncthreads();
        if (t < 128) sc[t] += a;
        __syncthreads();
    }
    if (t < 128) {
        int excl = sc[t] - c;
        loff[t] = excl;
        if (t < nd) {
            row_ptr[d0 + t] = (int)(b0 + (unsigned)excl);
            dinv[d0 + t] = rsqrtf(ldeg[t] + 1.0f);
        }
    }
    if (bkt == NBUCK - 1 && t == 0) row_ptr[N_NODES] = N_EDGES;
    __syncthreads();

    if (nb <= MAXB) {
        // pass 2: place raw edges into LDS at final (dst-sorted) order
        for (int i = t; i < nb; i += 256) {
            int2 e = pbuf[b0 + i];
            int s = e.x & 0x1FFFF;
            int dl = (e.x >> 17) & 127;
            unsigned r = atomicAdd(&lcur[dl], 1u);
            sorted[loff[dl] + (int)r] = make_int2(s, e.y);
        }
        __syncthreads();
        // coalesced streaming write-out
        for (int i = t; i < nb; i += 256) ebuf[b0 + i] = sorted[i];
    } else {
        // fallback (statistically unreachable): direct scattered writes
        for (int i = t; i < nb; i += 256) {
            int2 e = pbuf[b0 + i];
            int s = e.x & 0x1FFFF;
            int dl = (e.x >> 17) & 127;
            unsigned r = atomicAdd(&lcur[dl], 1u);
            ebuf[b0 + loff[dl] + r] = make_int2(s, e.y);
        }
    }
}

// ---------- one-time W1 swizzle into MFMA B-fragment order (bf16) ----------
__global__ void wswiz_kernel(const float* __restrict__ W, unsigned short* __restrict__ wsw) {
    int idx = blockIdx.x * blockDim.x + threadIdx.x;  // 0 .. 16383
    if (idx < NF * HID) {
        int j = idx & 7;
        int lane = (idx >> 3) & 63;
        int ntile = (idx >> 9) & 3;
        int kiter = idx >> 11;
        int k = kiter * 32 + (lane >> 4) * 8 + j;
        int n = ntile * 16 + (lane & 15);
        wsw[idx] = f2bf(W[k * HID + n]);
    }
}

// ---------- h' = dinv[row] * (x @ W1) via MFMA (bf16 in, fp32 acc, bf16 out) ----------
__launch_bounds__(256)
__global__ void gemm1_mfma(const float* __restrict__ x, const unsigned short* __restrict__ wsw,
                           const float* __restrict__ dinv, unsigned short* __restrict__ h) {
    int t = threadIdx.x;
    int lane = t & 63;
    int wave = t >> 6;
    int m = lane & 15;
    int quad = lane >> 4;
    int rowbase = blockIdx.x * 64 + wave * 16;

    int row = rowbase + m;
    if (row >= N_NODES) row = N_NODES - 1;

    const short8* wv = (const short8*)wsw;

    f32x4 acc[4] = {{0.f,0.f,0.f,0.f},{0.f,0.f,0.f,0.f},{0.f,0.f,0.f,0.f},{0.f,0.f,0.f,0.f}};

    const float* xrow = x + (size_t)row * NF;
#pragma unroll
    for (int kiter = 0; kiter < 8; ++kiter) {
        int k0 = kiter * 32 + quad * 8;
        float4 xa = *(const float4*)&xrow[k0];
        float4 xb = *(const float4*)&xrow[k0 + 4];
        short8 a;
        a[0] = (short)f2bf(xa.x); a[1] = (short)f2bf(xa.y);
        a[2] = (short)f2bf(xa.z); a[3] = (short)f2bf(xa.w);
        a[4] = (short)f2bf(xb.x); a[5] = (short)f2bf(xb.y);
        a[6] = (short)f2bf(xb.z); a[7] = (short)f2bf(xb.w);
#pragma unroll
        for (int nt = 0; nt < 4; ++nt) {
            short8 b = wv[(kiter * 4 + nt) * 64 + lane];
            acc[nt] = __builtin_amdgcn_mfma_f32_16x16x32_bf16(a, b, acc[nt], 0, 0, 0);
        }
    }

    float di[4];
#pragma unroll
    for (int r = 0; r < 4; ++r) {
        int orow = rowbase + quad * 4 + r;
        di[r] = (orow < N_NODES) ? dinv[orow] : 0.f;
    }

#pragma unroll
    for (int nt = 0; nt < 4; ++nt) {
#pragma unroll
        for (int r = 0; r < 4; ++r) {
            int orow = rowbase + quad * 4 + r;
            if (orow < N_NODES) {
                int ocol = nt * 16 + m;
                h[(size_t)orow * HID + ocol] = f2bf(di[r] * acc[nt][r]);
            }
        }
    }
}

// ---------- fused layer-1 aggregation + self-loop + bias + ELU + @W2 (dst quarter) ----------
// agg = dinv[d]*(sum_e ew*h'[s] + h'[d]) + b1;  z' = dinv[d]*(elu(agg)@W2)
__launch_bounds__(256)
__global__ void fused1_kernel(const int* __restrict__ row_ptr, const int2* __restrict__ ebuf,
                              const unsigned short* __restrict__ h,
                              const float* __restrict__ dinv, const float* __restrict__ b1,
                              const float* __restrict__ W2, float* __restrict__ z, int dbase) {
    int lane = threadIdx.x & 63;
    int d = dbase + ((blockIdx.x * blockDim.x + threadIdx.x) >> 6);
    if (d >= N_NODES || d >= dbase + NQ) return;

    int start = row_ptr[d];
    int end = row_ptr[d + 1];
    int f = lane & 15;
    int g = lane >> 4;

    const uint2* h64 = (const uint2*)h;

    float4 acc = make_float4(0.f, 0.f, 0.f, 0.f);

    for (int base = start; base < end; base += 64) {
        int n = end - base; if (n > 64) n = 64;
        int2 e = (lane < n) ? ebuf[base + lane] : make_int2(0, 0);
        int j = 0;
        for (; j + 16 <= n; j += 16) {
            uint2 hp[4]; float w[4];
#pragma unroll
            for (int u = 0; u < 4; ++u) {
                int idx = j + u * 4 + g;
                int s = __shfl(e.x, idx);
                w[u] = __int_as_float(__shfl(e.y, idx));
                hp[u] = h64[(size_t)s * 16 + f];
            }
#pragma unroll
            for (int u = 0; u < 4; ++u) {
                acc.x = fmaf(w[u], bfl(hp[u].x), acc.x);
                acc.y = fmaf(w[u], bfh(hp[u].x), acc.y);
                acc.z = fmaf(w[u], bfl(hp[u].y), acc.z);
                acc.w = fmaf(w[u], bfh(hp[u].y), acc.w);
            }
        }
        for (; j + 4 <= n; j += 4) {
            int idx = j + g;
            int s = __shfl(e.x, idx);
            float w = __int_as_float(__shfl(e.y, idx));
            uint2 hp = h64[(size_t)s * 16 + f];
            acc.x = fmaf(w, bfl(hp.x), acc.x);
            acc.y = fmaf(w, bfh(hp.x), acc.y);
            acc.z = fmaf(w, bfl(hp.y), acc.z);
            acc.w = fmaf(w, bfh(hp.y), acc.w);
        }
        int rem = n - j;
        if (rem > 0) {
            int idx = j + (g < rem ? g : 0);
            int s = __shfl(e.x, idx);
            float w = __int_as_float(__shfl(e.y, idx));
            if (g < rem) {
                uint2 hp = h64[(size_t)s * 16 + f];
                acc.x = fmaf(w, bfl(hp.x), acc.x);
                acc.y = fmaf(w, bfh(hp.x), acc.y);
                acc.z = fmaf(w, bfl(hp.y), acc.z);
                acc.w = fmaf(w, bfh(hp.y), acc.w);
            }
        }
    }

    acc.x += __shfl_down(acc.x, 32); acc.y += __shfl_down(acc.y, 32);
    acc.z += __shfl_down(acc.z, 32); acc.w += __shfl_down(acc.w, 32);
    acc.x += __shfl_down(acc.x, 16); acc.y += __shfl_down(acc.y, 16);
    acc.z += __shfl_down(acc.z, 16); acc.w += __shfl_down(acc.w, 16);

    float di = dinv[d];
    uint2 hd = h64[(size_t)d * 16 + f];   // h' already carries dinv[d]
    float4 b = *(const float4*)&b1[4 * f];
    float4 w2 = *(const float4*)&W2[4 * f];

    float v0 = di * (acc.x + bfl(hd.x)) + b.x;
    float v1 = di * (acc.y + bfh(hd.x)) + b.y;
    float v2 = di * (acc.z + bfl(hd.y)) + b.z;
    float v3 = di * (acc.w + bfh(hd.y)) + b.w;
    v0 = (v0 > 0.f) ? v0 : (__expf(v0) - 1.f);
    v1 = (v1 > 0.f) ? v1 : (__expf(v1) - 1.f);
    v2 = (v2 > 0.f) ? v2 : (__expf(v2) - 1.f);
    v3 = (v3 > 0.f) ? v3 : (__expf(v3) - 1.f);

    float p = v0 * w2.x + v1 * w2.y + v2 * w2.z + v3 * w2.w;
    p += __shfl_down(p, 8);
    p += __shfl_down(p, 4);
    p += __shfl_down(p, 2);
    p += __shfl_down(p, 1);
    if (lane == 0) z[d] = di * p;        // z' = dinv[d] * z
}

// ---------- fused layer-2 aggregation + self-loop + bias + sigmoid ----------
// v = dinv[d]*(sum_e ew*z'[s] + z'[d]) + b2
__launch_bounds__(256)
__global__ void fused2_kernel(const int* __restrict__ row_ptr, const int2* __restrict__ ebuf,
                              const float* __restrict__ z, const float* __restrict__ dinv,
                              const float* __restrict__ b2, float* __restrict__ out) {
    int lane = threadIdx.x & 63;
    int d = (blockIdx.x * blockDim.x + threadIdx.x) >> 6;
    if (d >= N_NODES) return;

    int start = row_ptr[d];
    int end = row_ptr[d + 1];

    float acc = 0.0f;
    for (int i = start + lane; i < end; i += 64) {
        int2 e = ebuf[i];
        acc = fmaf(__int_as_float(e.y), z[e.x], acc);
    }
#pragma unroll
    for (int off = 32; off > 0; off >>= 1) acc += __shfl_down(acc, off);

    if (lane == 0) {
        float di = dinv[d];
        float v = di * (acc + z[d]) + b2[0];
        out[d] = 1.0f / (1.0f + __expf(-v));
    }
}

extern "C" void kernel_launch(void* const* d_in, const int* in_sizes, int n_in,
                              void* d_out, int out_size, void* d_ws, size_t ws_size,
                              hipStream_t stream) {
    const float* x  = (const float*)d_in[0];
    const int*   ei = (const int*)d_in[1];
    const float* ew = (const float*)d_in[2];
    const float* W1 = (const float*)d_in[3];
    const float* b1 = (const float*)d_in[4];
    const float* W2 = (const float*)d_in[5];
    const float* b2 = (const float*)d_in[6];
    float* out = (float*)d_out;

    char* ws = (char*)d_ws;
    unsigned int* blkhist = (unsigned int*)ws;                  ws += (size_t)NP1 * NBUCK * 4;
    unsigned int* blkbase = (unsigned int*)ws;                  ws += (size_t)NBUCK * NP1 * 4;
    unsigned int* total   = (unsigned int*)ws;                  ws += (size_t)NBUCK * 4;
    unsigned int* base    = (unsigned int*)ws;                  ws += (size_t)(NBUCK + 1) * 4;
    float* dinv    = (float*)ws;                                ws += (size_t)N_NODES * 4;
    int*   row_ptr = (int*)ws;                                  ws += (size_t)(N_NODES + 1) * 4;
    int2*  pbuf    = (int2*)ws;                                 ws += (size_t)N_EDGES * 8;
    int2*  ebuf    = (int2*)ws;                                 ws += (size_t)N_EDGES * 8;
    unsigned short* h = (unsigned short*)ws;                    ws += (size_t)N_NODES * HID * 2;
    unsigned short* wsw = (unsigned short*)ws;                  ws += (size_t)NF * HID * 2;
    float* z       = (float*)ws;                                ws += (size_t)N_NODES * 4;

    p1count<<<NP1, 256, 0, stream>>>(ei, blkhist);
    bktA<<<NBUCK, 256, 0, stream>>>(blkhist, total);
    bktB<<<1, 1024, 0, stream>>>(total, base);
    bktC<<<NBUCK, 256, 0, stream>>>(blkhist, base, blkbase);
    p1scatter<<<NP1, 256, 0, stream>>>(ei, ew, blkhist, blkbase, pbuf);
    p2ab<<<NBUCK, 256, 0, stream>>>(pbuf, base, dinv, row_ptr, ebuf);

    wswiz_kernel<<<(NF * HID + 255) / 256, 256, 0, stream>>>(W1, wsw);
    gemm1_mfma<<<(N_NODES + 63) / 64, 256, 0, stream>>>(x, wsw, dinv, h);

    int qgrid = (NQ * 64) / 256;   // 6250 blocks per quarter
    fused1_kernel<<<qgrid, 256, 0, stream>>>(row_ptr, ebuf, h, dinv, b1, W2, z, 0);
    fused1_kernel<<<qgrid, 256, 0, stream>>>(row_ptr, ebuf, h, dinv, b1, W2, z, NQ);
    fused1_kernel<<<qgrid, 256, 0, stream>>>(row_ptr, ebuf, h, dinv, b1, W2, z, 2 * NQ);
    fused1_kernel<<<qgrid, 256, 0, stream>>>(row_ptr, ebuf, h, dinv, b1, W2, z, 3 * NQ);

    int grid = (N_NODES * 64 + 255) / 256;
    fused2_kernel<<<grid, 256, 0, stream>>>(row_ptr, ebuf, z, dinv, b2, out);
}

// Round 9
// 392.851 us; speedup vs baseline: 4.1926x; 1.0107x over previous
//
#include <hip/hip_runtime.h>

#define N_NODES 100000
#define N_EDGES 3200000
#define NF 256
#define HID 64
#define BSHIFT 7
#define NBUCK 782                       // ceil(100000 / 128)
#define NP1 512                         // phase-1 partition blocks
#define CHUNKE (N_EDGES / NP1)          // 6250 exactly (even)
#define MAXB 5120                       // p2ab LDS sort capacity per bucket (mean 4096, ~16 sigma)
#define NQ 25000                        // dsts per fused1 quarter

typedef short short8 __attribute__((ext_vector_type(8)));
typedef float f32x4 __attribute__((ext_vector_type(4)));

__device__ __forceinline__ unsigned short f2bf(float v) {
    unsigned int u = __float_as_uint(v);
    u += 0x7FFFu + ((u >> 16) & 1u);
    return (unsigned short)(u >> 16);
}
__device__ __forceinline__ float bfl(unsigned int p) { return __uint_as_float((p & 0xFFFFu) << 16); }
__device__ __forceinline__ float bfh(unsigned int p) { return __uint_as_float(p & 0xFFFF0000u); }

// ---------- 1a: per-block LDS histogram + folded one-time W1 swizzle ----------
__launch_bounds__(256)
__global__ void p1count(const int* __restrict__ ei, unsigned int* __restrict__ blkhist,
                        const float* __restrict__ W, unsigned short* __restrict__ wsw) {
    __shared__ unsigned int hist[NBUCK];
    // folded wswiz: blocks 0..63 each swizzle 256 elements (total 16384)
    if (blockIdx.x < 64) {
        int idx = blockIdx.x * 256 + threadIdx.x;
        int j = idx & 7;
        int lane = (idx >> 3) & 63;
        int ntile = (idx >> 9) & 3;
        int kiter = idx >> 11;
        int k = kiter * 32 + (lane >> 4) * 8 + j;
        int n = ntile * 16 + (lane & 15);
        wsw[idx] = f2bf(W[k * HID + n]);
    }
    for (int i = threadIdx.x; i < NBUCK; i += 256) hist[i] = 0;
    __syncthreads();
    int lo = blockIdx.x * CHUNKE;
    int hi = lo + CHUNKE;
    for (int e = lo + 2 * threadIdx.x; e < hi; e += 512) {
        int2 d2 = *(const int2*)&ei[N_EDGES + e];
        atomicAdd(&hist[((unsigned)d2.x) >> BSHIFT], 1u);
        atomicAdd(&hist[((unsigned)d2.y) >> BSHIFT], 1u);
    }
    __syncthreads();
    unsigned int* row = blkhist + (size_t)blockIdx.x * NBUCK;
    for (int i = threadIdx.x; i < NBUCK; i += 256) row[i] = hist[i];
}

// ---------- 1b: column reduce -> bucket_total[bucket] ----------
__launch_bounds__(256)
__global__ void bktA(const unsigned int* __restrict__ blkhist, unsigned int* __restrict__ total) {
    __shared__ unsigned int sh[256];
    int i = blockIdx.x;              // bucket
    int t = threadIdx.x;
    unsigned s = 0;
    for (int b = t; b < NP1; b += 256) s += blkhist[(size_t)b * NBUCK + i];
    sh[t] = s;
    __syncthreads();
    for (int off = 128; off > 0; off >>= 1) {
        if (t < off) sh[t] += sh[t + off];
        __syncthreads();
    }
    if (t == 0) total[i] = sh[0];
}

// ---------- 1cd merged: per-block base_i reduction + per-bucket scan across blocks ----------
// Each block i: base_i = sum_{j<i} total[j] (L2-hot), writes base[i], then
// absolute blkbase[i][b] = base_i + exclusive prefix over blocks.
__launch_bounds__(256)
__global__ void bktC(const unsigned int* __restrict__ blkhist, const unsigned int* __restrict__ total,
                     unsigned int* __restrict__ blkbase, unsigned int* __restrict__ base) {
    __shared__ unsigned int sh[256];
    int i = blockIdx.x;              // bucket
    int t = threadIdx.x;

    // ---- base_i = exclusive prefix of total[] at i ----
    unsigned bs = 0;
    for (int j = t; j < i; j += 256) bs += total[j];
    sh[t] = bs;
    __syncthreads();
    for (int off = 128; off > 0; off >>= 1) {
        if (t < off) sh[t] += sh[t + off];
        __syncthreads();
    }
    unsigned base_i = sh[0];
    __syncthreads();
    if (t == 0) {
        base[i] = base_i;
        if (i == 0) base[NBUCK] = N_EDGES;
    }

    // ---- per-bucket scan across the 512 phase-1 blocks ----
    unsigned c[2];
    unsigned s = 0;
#pragma unroll
    for (int j = 0; j < 2; ++j) {
        c[j] = blkhist[(size_t)(2 * t + j) * NBUCK + i];
        s += c[j];
    }
    sh[t] = s;
    __syncthreads();
    for (int off = 1; off < 256; off <<= 1) {
        unsigned a = (t >= off) ? sh[t - off] : 0;
        __syncthreads();
        sh[t] += a;
        __syncthreads();
    }
    unsigned run = base_i + sh[t] - s;
    unsigned int* orow = blkbase + (size_t)i * NP1 + 2 * t;
    orow[0] = run; run += c[0];
    orow[1] = run;
}

// ---------- 1e: staged scatter — LDS counting sort, then coalesced run write-out ----------
// pbuf entry: x = src | (dst_low7 << 17), y = ew bits.  int2/float2 edge loads.
__launch_bounds__(256)
__global__ void p1scatter(const int* __restrict__ ei, const float* __restrict__ ew,
                          const unsigned int* __restrict__ blkhist,
                          const unsigned int* __restrict__ blkbase, int2* __restrict__ pbuf) {
    __shared__ int2 sorted[CHUNKE];           // 50000 B
    __shared__ unsigned int loff[NBUCK + 2];
    __shared__ unsigned int cur[NBUCK];
    __shared__ unsigned int sh[256];

    int t = threadIdx.x;
    int b = blockIdx.x;

    unsigned u[4];
    unsigned s = 0;
#pragma unroll
    for (int j = 0; j < 4; ++j) {
        int idx = 4 * t + j;
        u[j] = (idx < NBUCK) ? blkhist[(size_t)b * NBUCK + idx] : 0u;
        s += u[j];
    }
    sh[t] = s;
    __syncthreads();
    for (int off = 1; off < 256; off <<= 1) {
        unsigned a = (t >= off) ? sh[t - off] : 0;
        __syncthreads();
        sh[t] += a;
        __syncthreads();
    }
    unsigned run = sh[t] - s;
#pragma unroll
    for (int j = 0; j < 4; ++j) {
        int idx = 4 * t + j;
        if (idx <= NBUCK) loff[idx] = run;
        run += u[j];
        if (idx < NBUCK) cur[idx] = 0;
    }
    __syncthreads();

    int lo = b * CHUNKE;
    int hi = lo + CHUNKE;
    for (int e = lo + 2 * t; e < hi; e += 512) {
        int2 s2 = *(const int2*)&ei[e];
        int2 d2 = *(const int2*)&ei[N_EDGES + e];
        float2 w2 = *(const float2*)&ew[e];
        unsigned k0 = ((unsigned)d2.x) >> BSHIFT;
        unsigned r0 = atomicAdd(&cur[k0], 1u);
        sorted[loff[k0] + r0] = make_int2(s2.x | (int)(((unsigned)d2.x & 127u) << 17), __float_as_int(w2.x));
        unsigned k1 = ((unsigned)d2.y) >> BSHIFT;
        unsigned r1 = atomicAdd(&cur[k1], 1u);
        sorted[loff[k1] + r1] = make_int2(s2.y | (int)(((unsigned)d2.y & 127u) << 17), __float_as_int(w2.y));
    }
    __syncthreads();

    int lane = t & 63;
    int wave = t >> 6;
    int q = lane >> 3;
    int r8 = lane & 7;
    for (int k0 = wave * 8; k0 < NBUCK; k0 += 32) {
        int k = k0 + q;
        if (k < NBUCK) {
            unsigned off = loff[k];
            int n = (int)(loff[k + 1] - off);
            unsigned gb = blkbase[(size_t)k * NP1 + b];
            for (int i = r8; i < n; i += 8)
                pbuf[gb + i] = sorted[off + i];
        }
    }
}

// ---------- phase 2 (merged): cnt + weighted deg + dinv + scan + LDS sort + coalesced CSR ----------
// ebuf stores RAW edge weight; dinv[s]/dinv[d] are folded into h' and z' downstream.
__launch_bounds__(256)
__global__ void p2ab(const int2* __restrict__ pbuf, const unsigned int* __restrict__ base,
                     float* __restrict__ dinv, int* __restrict__ row_ptr,
                     int2* __restrict__ ebuf) {
    __shared__ int lcnt[128];
    __shared__ float ldeg[128];
    __shared__ int sc[128];
    __shared__ int loff[128];
    __shared__ unsigned int lcur[128];
    __shared__ int2 sorted[MAXB];    // 40 KB

    int t = threadIdx.x;
    int bkt = blockIdx.x;
    unsigned b0 = base[bkt], bh = base[bkt + 1];
    int nb = (int)(bh - b0);
    int d0 = bkt << BSHIFT;
    int nd = N_NODES - d0; if (nd > 128) nd = 128;

    if (t < 128) { lcnt[t] = 0; ldeg[t] = 0.f; lcur[t] = 0; }
    __syncthreads();

    // pass 1: per-dst counts + weighted degree
    for (int i = t; i < nb; i += 256) {
        int2 e = pbuf[b0 + i];
        int dl = (e.x >> 17) & 127;
        atomicAdd(&lcnt[dl], 1);
        atomicAdd(&ldeg[dl], __int_as_float(e.y));
    }
    __syncthreads();

    // inclusive scan over 128 counts
    int c = (t < 128) ? lcnt[t] : 0;
    if (t < 128) sc[t] = c;
    __syncthreads();
    for (int off = 1; off < 128; off <<= 1) {
        int a = (t < 128 && t >= off) ? sc[t - off] : 0;
        __syncthreads();
        if (t < 128) sc[t] += a;
        __syncthreads();
    }
    if (t < 128) {
        int excl = sc[t] - c;
        loff[t] = excl;
        if (t < nd) {
            row_ptr[d0 + t] = (int)(b0 + (unsigned)excl);
            dinv[d0 + t] = rsqrtf(ldeg[t] + 1.0f);
        }
    }
    if (bkt == NBUCK - 1 && t == 0) row_ptr[N_NODES] = N_EDGES;
    __syncthreads();

    if (nb <= MAXB) {
        // pass 2: place raw edges into LDS at final (dst-sorted) order
        for (int i = t; i < nb; i += 256) {
            int2 e = pbuf[b0 + i];
            int s = e.x & 0x1FFFF;
            int dl = (e.x >> 17) & 127;
            unsigned r = atomicAdd(&lcur[dl], 1u);
            sorted[loff[dl] + (int)r] = make_int2(s, e.y);
        }
        __syncthreads();
        // coalesced streaming write-out
        for (int i = t; i < nb; i += 256) ebuf[b0 + i] = sorted[i];
    } else {
        // fallback (statistically unreachable): direct scattered writes
        for (int i = t; i < nb; i += 256) {
            int2 e = pbuf[b0 + i];
            int s = e.x & 0x1FFFF;
            int dl = (e.x >> 17) & 127;
            unsigned r = atomicAdd(&lcur[dl], 1u);
            ebuf[b0 + loff[dl] + r] = make_int2(s, e.y);
        }
    }
}

// ---------- h' = dinv[row] * (x @ W1) via MFMA (bf16 in, fp32 acc, bf16 out) ----------
__launch_bounds__(256)
__global__ void gemm1_mfma(const float* __restrict__ x, const unsigned short* __restrict__ wsw,
                           const float* __restrict__ dinv, unsigned short* __restrict__ h) {
    int t = threadIdx.x;
    int lane = t & 63;
    int wave = t >> 6;
    int m = lane & 15;
    int quad = lane >> 4;
    int rowbase = blockIdx.x * 64 + wave * 16;

    int row = rowbase + m;
    if (row >= N_NODES) row = N_NODES - 1;

    const short8* wv = (const short8*)wsw;

    f32x4 acc[4] = {{0.f,0.f,0.f,0.f},{0.f,0.f,0.f,0.f},{0.f,0.f,0.f,0.f},{0.f,0.f,0.f,0.f}};

    const float* xrow = x + (size_t)row * NF;
#pragma unroll
    for (int kiter = 0; kiter < 8; ++kiter) {
        int k0 = kiter * 32 + quad * 8;
        float4 xa = *(const float4*)&xrow[k0];
        float4 xb = *(const float4*)&xrow[k0 + 4];
        short8 a;
        a[0] = (short)f2bf(xa.x); a[1] = (short)f2bf(xa.y);
        a[2] = (short)f2bf(xa.z); a[3] = (short)f2bf(xa.w);
        a[4] = (short)f2bf(xb.x); a[5] = (short)f2bf(xb.y);
        a[6] = (short)f2bf(xb.z); a[7] = (short)f2bf(xb.w);
#pragma unroll
        for (int nt = 0; nt < 4; ++nt) {
            short8 b = wv[(kiter * 4 + nt) * 64 + lane];
            acc[nt] = __builtin_amdgcn_mfma_f32_16x16x32_bf16(a, b, acc[nt], 0, 0, 0);
        }
    }

    float di[4];
#pragma unroll
    for (int r = 0; r < 4; ++r) {
        int orow = rowbase + quad * 4 + r;
        di[r] = (orow < N_NODES) ? dinv[orow] : 0.f;
    }

#pragma unroll
    for (int nt = 0; nt < 4; ++nt) {
#pragma unroll
        for (int r = 0; r < 4; ++r) {
            int orow = rowbase + quad * 4 + r;
            if (orow < N_NODES) {
                int ocol = nt * 16 + m;
                h[(size_t)orow * HID + ocol] = f2bf(di[r] * acc[nt][r]);
            }
        }
    }
}

// ---------- fused layer-1 aggregation + self-loop + bias + ELU + @W2 (dst quarter) ----------
// agg = dinv[d]*(sum_e ew*h'[s] + h'[d]) + b1;  z' = dinv[d]*(elu(agg)@W2)
__launch_bounds__(256)
__global__ void fused1_kernel(const int* __restrict__ row_ptr, const int2* __restrict__ ebuf,
                              const unsigned short* __restrict__ h,
                              const float* __restrict__ dinv, const float* __restrict__ b1,
                              const float* __restrict__ W2, float* __restrict__ z, int dbase) {
    int lane = threadIdx.x & 63;
    int d = dbase + ((blockIdx.x * blockDim.x + threadIdx.x) >> 6);
    if (d >= N_NODES || d >= dbase + NQ) return;

    int start = row_ptr[d];
    int end = row_ptr[d + 1];
    int f = lane & 15;
    int g = lane >> 4;

    const uint2* h64 = (const uint2*)h;

    float4 acc = make_float4(0.f, 0.f, 0.f, 0.f);

    for (int base = start; base < end; base += 64) {
        int n = end - base; if (n > 64) n = 64;
        int2 e = (lane < n) ? ebuf[base + lane] : make_int2(0, 0);
        int j = 0;
        for (; j + 16 <= n; j += 16) {
            uint2 hp[4]; float w[4];
#pragma unroll
            for (int u = 0; u < 4; ++u) {
                int idx = j + u * 4 + g;
                int s = __shfl(e.x, idx);
                w[u] = __int_as_float(__shfl(e.y, idx));
                hp[u] = h64[(size_t)s * 16 + f];
            }
#pragma unroll
            for (int u = 0; u < 4; ++u) {
                acc.x = fmaf(w[u], bfl(hp[u].x), acc.x);
                acc.y = fmaf(w[u], bfh(hp[u].x), acc.y);
                acc.z = fmaf(w[u], bfl(hp[u].y), acc.z);
                acc.w = fmaf(w[u], bfh(hp[u].y), acc.w);
            }
        }
        for (; j + 4 <= n; j += 4) {
            int idx = j + g;
            int s = __shfl(e.x, idx);
            float w = __int_as_float(__shfl(e.y, idx));
            uint2 hp = h64[(size_t)s * 16 + f];
            acc.x = fmaf(w, bfl(hp.x), acc.x);
            acc.y = fmaf(w, bfh(hp.x), acc.y);
            acc.z = fmaf(w, bfl(hp.y), acc.z);
            acc.w = fmaf(w, bfh(hp.y), acc.w);
        }
        int rem = n - j;
        if (rem > 0) {
            int idx = j + (g < rem ? g : 0);
            int s = __shfl(e.x, idx);
            float w = __int_as_float(__shfl(e.y, idx));
            if (g < rem) {
                uint2 hp = h64[(size_t)s * 16 + f];
                acc.x = fmaf(w, bfl(hp.x), acc.x);
                acc.y = fmaf(w, bfh(hp.x), acc.y);
                acc.z = fmaf(w, bfl(hp.y), acc.z);
                acc.w = fmaf(w, bfh(hp.y), acc.w);
            }
        }
    }

    acc.x += __shfl_down(acc.x, 32); acc.y += __shfl_down(acc.y, 32);
    acc.z += __shfl_down(acc.z, 32); acc.w += __shfl_down(acc.w, 32);
    acc.x += __shfl_down(acc.x, 16); acc.y += __shfl_down(acc.y, 16);
    acc.z += __shfl_down(acc.z, 16); acc.w += __shfl_down(acc.w, 16);

    float di = dinv[d];
    uint2 hd = h64[(size_t)d * 16 + f];   // h' already carries dinv[d]
    float4 b = *(const float4*)&b1[4 * f];
    float4 w2 = *(const float4*)&W2[4 * f];

    float v0 = di * (acc.x + bfl(hd.x)) + b.x;
    float v1 = di * (acc.y + bfh(hd.x)) + b.y;
    float v2 = di * (acc.z + bfl(hd.y)) + b.z;
    float v3 = di * (acc.w + bfh(hd.y)) + b.w;
    v0 = (v0 > 0.f) ? v0 : (__expf(v0) - 1.f);
    v1 = (v1 > 0.f) ? v1 : (__expf(v1) - 1.f);
    v2 = (v2 > 0.f) ? v2 : (__expf(v2) - 1.f);
    v3 = (v3 > 0.f) ? v3 : (__expf(v3) - 1.f);

    float p = v0 * w2.x + v1 * w2.y + v2 * w2.z + v3 * w2.w;
    p += __shfl_down(p, 8);
    p += __shfl_down(p, 4);
    p += __shfl_down(p, 2);
    p += __shfl_down(p, 1);
    if (lane == 0) z[d] = di * p;        // z' = dinv[d] * z
}

// ---------- fused layer-2 aggregation + self-loop + bias + sigmoid ----------
// v = dinv[d]*(sum_e ew*z'[s] + z'[d]) + b2
__launch_bounds__(256)
__global__ void fused2_kernel(const int* __restrict__ row_ptr, const int2* __restrict__ ebuf,
                              const float* __restrict__ z, const float* __restrict__ dinv,
                              const float* __restrict__ b2, float* __restrict__ out) {
    int lane = threadIdx.x & 63;
    int d = (blockIdx.x * blockDim.x + threadIdx.x) >> 6;
    if (d >= N_NODES) return;

    int start = row_ptr[d];
    int end = row_ptr[d + 1];

    float acc = 0.0f;
    for (int i = start + lane; i < end; i += 64) {
        int2 e = ebuf[i];
        acc = fmaf(__int_as_float(e.y), z[e.x], acc);
    }
#pragma unroll
    for (int off = 32; off > 0; off >>= 1) acc += __shfl_down(acc, off);

    if (lane == 0) {
        float di = dinv[d];
        float v = di * (acc + z[d]) + b2[0];
        out[d] = 1.0f / (1.0f + __expf(-v));
    }
}

extern "C" void kernel_launch(void* const* d_in, const int* in_sizes, int n_in,
                              void* d_out, int out_size, void* d_ws, size_t ws_size,
                              hipStream_t stream) {
    const float* x  = (const float*)d_in[0];
    const int*   ei = (const int*)d_in[1];
    const float* ew = (const float*)d_in[2];
    const float* W1 = (const float*)d_in[3];
    const float* b1 = (const float*)d_in[4];
    const float* W2 = (const float*)d_in[5];
    const float* b2 = (const float*)d_in[6];
    float* out = (float*)d_out;

    char* ws = (char*)d_ws;
    unsigned int* blkhist = (unsigned int*)ws;                  ws += (size_t)NP1 * NBUCK * 4;
    unsigned int* blkbase = (unsigned int*)ws;                  ws += (size_t)NBUCK * NP1 * 4;
    unsigned int* total   = (unsigned int*)ws;                  ws += (size_t)NBUCK * 4;
    unsigned int* base    = (unsigned int*)ws;                  ws += (size_t)(NBUCK + 1) * 4;
    float* dinv    = (float*)ws;                                ws += (size_t)N_NODES * 4;
    int*   row_ptr = (int*)ws;                                  ws += (size_t)(N_NODES + 1) * 4;
    int2*  pbuf    = (int2*)ws;                                 ws += (size_t)N_EDGES * 8;
    int2*  ebuf    = (int2*)ws;                                 ws += (size_t)N_EDGES * 8;
    unsigned short* h = (unsigned short*)ws;                    ws += (size_t)N_NODES * HID * 2;
    unsigned short* wsw = (unsigned short*)ws;                  ws += (size_t)NF * HID * 2;
    float* z       = (float*)ws;                                ws += (size_t)N_NODES * 4;

    p1count<<<NP1, 256, 0, stream>>>(ei, blkhist, W1, wsw);
    bktA<<<NBUCK, 256, 0, stream>>>(blkhist, total);
    bktC<<<NBUCK, 256, 0, stream>>>(blkhist, total, blkbase, base);
    p1scatter<<<NP1, 256, 0, stream>>>(ei, ew, blkhist, blkbase, pbuf);
    p2ab<<<NBUCK, 256, 0, stream>>>(pbuf, base, dinv, row_ptr, ebuf);

    gemm1_mfma<<<(N_NODES + 63) / 64, 256, 0, stream>>>(x, wsw, dinv, h);

    int qgrid = (NQ * 64) / 256;   // 6250 blocks per quarter
    fused1_kernel<<<qgrid, 256, 0, stream>>>(row_ptr, ebuf, h, dinv, b1, W2, z, 0);
    fused1_kernel<<<qgrid, 256, 0, stream>>>(row_ptr, ebuf, h, dinv, b1, W2, z, NQ);
    fused1_kernel<<<qgrid, 256, 0, stream>>>(row_ptr, ebuf, h, dinv, b1, W2, z, 2 * NQ);
    fused1_kernel<<<qgrid, 256, 0, stream>>>(row_ptr, ebuf, h, dinv, b1, W2, z, 3 * NQ);

    int grid = (N_NODES * 64 + 255) / 256;
    fused2_kernel<<<grid, 256, 0, stream>>>(row_ptr, ebuf, z, dinv, b2, out);
}